// Round 1
// baseline (526.905 us; speedup 1.0000x reference)
//
#include <hip/hip_runtime.h>
#include <cstdint>
#include <cstddef>

#define Bn   128
#define Rn   500
#define Nn   500
#define Kn   10
#define En   128
#define H1n  640
#define KEn  1280
#define Mn   (Bn * Rn)   // 64000 rows

typedef short s16x8 __attribute__((ext_vector_type(8)));
typedef float f32x4 __attribute__((ext_vector_type(4)));

// fp32 -> bf16 round-to-nearest-even (finite inputs)
__device__ __forceinline__ unsigned short f2bf(float x) {
    union { float f; unsigned int u; } v; v.f = x;
    unsigned int r = v.u + 0x7fffu + ((v.u >> 16) & 1u);
    return (unsigned short)(r >> 16);
}
__device__ __forceinline__ float bf2f(unsigned short u) {
    union { unsigned int u; float f; } v; v.u = ((unsigned int)u) << 16;
    return v.f;
}
// async 16B global->LDS (wave-uniform LDS base + lane*16)
__device__ __forceinline__ void gl2lds16(const void* g, void* l) {
    __builtin_amdgcn_global_load_lds(
        (const __attribute__((address_space(1))) unsigned int*)g,
        (__attribute__((address_space(3))) unsigned int*)l, 16, 0, 0);
}
// full drain: used ONLY outside the main loops (end-of-kernel DMA cleanup).
__device__ __forceinline__ void drain_all() {
    asm volatile("s_waitcnt vmcnt(0) lgkmcnt(0)" ::: "memory");
}
// counted vmcnt: retire the oldest (outstanding-N) DMAs, keep N in flight
// ACROSS the barrier (T4). vmcnt retires in issue order (m135).
#define WAITV(n) asm volatile("s_waitcnt vmcnt(" #n ")" ::: "memory")
// bare barrier (NO implicit vmcnt(0) drain, unlike __syncthreads) + fences
// so the compiler cannot hoist LDS reads of the new tile above it.
__device__ __forceinline__ void pipe_barrier() {
    __builtin_amdgcn_s_barrier();
    asm volatile("" ::: "memory");
    __builtin_amdgcn_sched_barrier(0);
}

// ---------------- kernel 1: fp32 -> bf16 conversions (encoded, w1, w2) ----------------
__global__ void convw_kernel(const float* __restrict__ enc, const float* __restrict__ w1,
                             const float* __restrict__ w2,
                             unsigned short* __restrict__ encb, unsigned short* __restrict__ w1b,
                             unsigned short* __restrict__ w2b) {
    int i = blockIdx.x * 256 + threadIdx.x;   // float4 group index
    if (i < (Bn * Nn * En) / 4) {
        float4 v = ((const float4*)enc)[i];
        ushort4 o; o.x = f2bf(v.x); o.y = f2bf(v.y); o.z = f2bf(v.z); o.w = f2bf(v.w);
        ((ushort4*)encb)[i] = o;
    }
    if (i < (H1n * KEn) / 4) {
        float4 v = ((const float4*)w1)[i];
        ushort4 o; o.x = f2bf(v.x); o.y = f2bf(v.y); o.z = f2bf(v.z); o.w = f2bf(v.w);
        ((ushort4*)w1b)[i] = o;
    }
    if (i < (En * H1n) / 4) {
        float4 v = ((const float4*)w2)[i];
        ushort4 o; o.x = f2bf(v.x); o.y = f2bf(v.y); o.z = f2bf(v.z); o.w = f2bf(v.w);
        ((ushort4*)w2b)[i] = o;
    }
}

// ---------------- kernel 2: fused top-K + pad-avg mean ----------------
// One wave per (b,r) row. Top-10 via u64 (bits(dist),idx) min-reduction (stable,
// ascending; +inf -> pad id N). Winners are wave-uniform, so the same wave then
// accumulates the mean of the valid gathered embeddings (u32 = 2 bf16 per lane).
__global__ __launch_bounds__(256) void select_kernel(const int* __restrict__ current,
                            const float* __restrict__ distance,
                            const float* __restrict__ masked,
                            const unsigned short* __restrict__ encb,
                            int* __restrict__ idx_out,
                            unsigned short* __restrict__ meanbb) {
    const int row  = blockIdx.x * 4 + (threadIdx.x >> 6);
    const int lane = threadIdx.x & 63;
    const int b    = row / Rn;
    const int cur  = current[row];
    const unsigned int* drow = (const unsigned int*)(distance + ((size_t)b * Nn + cur) * Nn);
    const unsigned int* mrow = (const unsigned int*)(masked + (size_t)row * Nn);

    unsigned long long key[8];
#pragma unroll
    for (int i = 0; i < 8; ++i) {
        int nn = lane + 64 * i;
        unsigned int fb = 0x7F800000u;            // +inf
        if (nn < Nn) {
            unsigned int m = mrow[nn];
            unsigned int d = drow[nn];
            fb = (m == 0xFF800000u) ? 0x7F800000u : d;   // visited -> +inf
        }
        key[i] = ((unsigned long long)fb << 32) | (unsigned int)nn;
    }

    int ids[Kn];          // wave-uniform winners (unrolled => static indexing)
    int myid = Nn;        // ids[lane] for lanes 0..9 (for the idx store)
#pragma unroll
    for (int it = 0; it < Kn; ++it) {
        unsigned long long bk = key[0];
#pragma unroll
        for (int i = 1; i < 8; ++i) bk = (key[i] < bk) ? key[i] : bk;
#pragma unroll
        for (int off = 1; off < 64; off <<= 1) {
            unsigned long long ok = __shfl_xor(bk, off);
            bk = (ok < bk) ? ok : bk;
        }
        const int wid = ((bk >> 32) == 0x7F800000u) ? Nn : (int)(bk & 0xffffffffu);
        ids[it] = wid;
        if (lane == it) myid = wid;
#pragma unroll
        for (int i = 0; i < 8; ++i)
            if (key[i] == bk) key[i] = 0x7F800000FFFFFFFFull;  // knock out winner
    }
    if (lane < Kn) idx_out[row * Kn + lane] = myid;

    // ---- mean phase: lane handles embedding dims {2*lane, 2*lane+1} ----
    const unsigned int* encu = (const unsigned int*)(encb + (size_t)b * Nn * En);
    float s0 = 0.f, s1 = 0.f; int cnt = 0;
#pragma unroll
    for (int k = 0; k < Kn; ++k) {
        const int id = ids[k];
        if (id < Nn) {
            unsigned int u = encu[id * (En / 2) + lane];
            s0 += bf2f((unsigned short)(u & 0xffffu));
            s1 += bf2f((unsigned short)(u >> 16));
            cnt++;
        }
    }
    float m0 = 0.f, m1 = 0.f;
    if (cnt > 0) { m0 = s0 / (float)cnt; m1 = s1 / (float)cnt; }
    unsigned int packed = (unsigned int)f2bf(m0) | ((unsigned int)f2bf(m1) << 16);
    ((unsigned int*)meanbb)[(size_t)row * (En / 2) + lane] = packed;
}

// ---------------- kernel 3: GEMM1, fused gather, BK=32, 3-stage counted-vmcnt pipeline ----
// Tile 128(M) x 128(H) x 32(K), 40 iters. Depth-2 prefetch: tile t+2 issued at
// iter t, so each tile's DMAs have ~2 iterations (>500 cyc) to land -> the per-
// iter wait is vmcnt(4) (retire tile t, keep 8 in flight across the barrier).
// 53 KB LDS -> 3 blocks/CU.
__global__ __launch_bounds__(256, 4) void gemm1_kernel(
        const unsigned short* __restrict__ encb, const unsigned short* __restrict__ meanbb,
        const int* __restrict__ idxb, const unsigned short* __restrict__ w1b,
        const float* __restrict__ b1, unsigned short* __restrict__ hbuf) {
    __shared__ alignas(16) unsigned short As[3][128 * 32];   // 3 x 8 KB
    __shared__ alignas(16) unsigned short Bs[3][128 * 32];   // 3 x 8 KB
    __shared__ int idxs[128 * Kn];                           // 5 KB

    // XCD-aware remap: 5 h-blocks of one m-block consecutive per XCD.
    const int p = blockIdx.x;
    const int L = (p & 7) * 313 + (p >> 3);
    if (L >= (Mn / 128) * (H1n / 128)) return;
    const int row0 = (L / 5) * 128;
    const int h0   = (L % 5) * 128;

    const int t    = threadIdx.x;
    const int lane = t & 63;
    const int wave = t >> 6;
    const int ln15 = lane & 15;
    const int q4   = lane >> 4;
    const int wm   = wave & 1;
    const int wn   = wave >> 1;

    // stage idx tile (contiguous 1280 ints)
    for (int i = t; i < 128 * Kn; i += 256) idxs[i] = idxb[row0 * Kn + i];

    // staging geometry: row stride 32 ushorts = 64 B = 4 x 16B chunks.
    // lane -> row rl = lane>>2, slot sc = lane&3; slot sc holds source chunk sc^(rl&3).
    const int rl   = lane >> 2;
    const int sc   = lane & 3;
    const int coff = (sc ^ (rl & 3)) * 8;   // source chunk offset (shorts)

    int lrow[2];
    const unsigned short* encB[2];
    const unsigned short* meanR[2];
    const unsigned short* w1R[2];
#pragma unroll
    for (int s = 0; s < 2; ++s) {
        lrow[s] = wave * 32 + s * 16 + rl;
        const int gr = row0 + lrow[s];
        const int bb = gr / Rn;
        encB[s]  = encb + (size_t)bb * Nn * En;
        meanR[s] = meanbb + (size_t)gr * En + coff;
        w1R[s]   = w1b + (size_t)(h0 + lrow[s]) * KEn + coff;
    }

    f32x4 acc[4][4];
#pragma unroll
    for (int i = 0; i < 4; ++i)
#pragma unroll
        for (int j = 0; j < 4; ++j)
            acc[i][j] = (f32x4){0.f, 0.f, 0.f, 0.f};

    auto issue = [&](int itk, int pb) {
        const int j   = itk >> 2;            // neighbor slot
        const int e0  = (itk & 3) * 32;      // quarter of the embedding row
        const int kk0 = itk * 32;
#pragma unroll
        for (int s = 0; s < 2; ++s) {
            const int id = idxs[lrow[s] * Kn + j];
            const unsigned short* srcA = (id < Nn)
                ? (encB[s] + (size_t)id * En + e0 + coff)
                : (meanR[s] + e0);
            gl2lds16(srcA, &As[pb][(wave * 32 + s * 16) * 32]);
            gl2lds16(w1R[s] + kk0, &Bs[pb][(wave * 32 + s * 16) * 32]);
        }
    };

    __syncthreads();          // idxs visible (full drain OK here, once)
    issue(0, 0);
    issue(1, 1);

    int cur = 0, nxt = 2;
    for (int itk = 0; itk < KEn / 32; ++itk) {
        WAITV(4);             // my tile-itk DMAs landed; 8 newer stay in flight
        pipe_barrier();       // all waves' tile-itk landed; prev reads done
        {
            int pre = itk + 2;                       // depth-2 prefetch
            if (pre > KEn / 32 - 1) pre = KEn / 32 - 1;   // tail: dummy re-issue
            issue(pre, nxt);                         // into dead buffer at tail
        }
        s16x8 af[4], bf[4];
#pragma unroll
        for (int i = 0; i < 4; ++i) {
            const int r = wm * 64 + i * 16 + ln15;
            af[i] = *(const s16x8*)&As[cur][r * 32 + (q4 ^ (r & 3)) * 8];
        }
#pragma unroll
        for (int jj = 0; jj < 4; ++jj) {
            const int r = wn * 64 + jj * 16 + ln15;
            bf[jj] = *(const s16x8*)&Bs[cur][r * 32 + (q4 ^ (r & 3)) * 8];
        }
#pragma unroll
        for (int i = 0; i < 4; ++i)
#pragma unroll
            for (int jj = 0; jj < 4; ++jj)
                acc[i][jj] = __builtin_amdgcn_mfma_f32_16x16x32_bf16(af[i], bf[jj], acc[i][jj], 0, 0, 0);
        cur = (cur == 2) ? 0 : cur + 1;
        nxt = (nxt == 2) ? 0 : nxt + 1;
    }
    drain_all();              // tail dummy DMAs must land before LDS is freed

    // ---- epilogue: bias + relu + bf16 store ----
#pragma unroll
    for (int i = 0; i < 4; ++i) {
#pragma unroll
        for (int jj = 0; jj < 4; ++jj) {
            const int h = h0 + wn * 64 + jj * 16 + ln15;
            const float bias = b1[h];
#pragma unroll
            for (int rg = 0; rg < 4; ++rg) {
                const int m = wm * 64 + i * 16 + q4 * 4 + rg;
                float vv = acc[i][jj][rg] + bias;
                vv = fmaxf(vv, 0.f);
                hbuf[(size_t)(row0 + m) * H1n + h] = f2bf(vv);
            }
        }
    }
}

// ---------------- kernel 4: GEMM2, BK=32, 3-stage counted-vmcnt pipeline ----------------
__global__ __launch_bounds__(256, 4) void gemm2_kernel(
        const unsigned short* __restrict__ hbuf, const unsigned short* __restrict__ w2b,
        const float* __restrict__ b2, float* __restrict__ out) {
    __shared__ alignas(16) unsigned short As[3][128 * 32];
    __shared__ alignas(16) unsigned short Bs[3][128 * 32];

    const int row0 = blockIdx.x * 128;
    const int t    = threadIdx.x;
    const int lane = t & 63;
    const int wave = t >> 6;
    const int ln15 = lane & 15;
    const int q4   = lane >> 4;
    const int wm   = wave & 1;
    const int wn   = wave >> 1;

    const int rl   = lane >> 2;
    const int sc   = lane & 3;
    const int coff = (sc ^ (rl & 3)) * 8;

    const unsigned short* hrow[2];
    const unsigned short* w2row[2];
#pragma unroll
    for (int s = 0; s < 2; ++s) {
        const int lr = wave * 32 + s * 16 + rl;
        hrow[s]  = hbuf + (size_t)(row0 + lr) * H1n + coff;
        w2row[s] = w2b + (size_t)lr * H1n + coff;
    }

    f32x4 acc[4][4];
#pragma unroll
    for (int i = 0; i < 4; ++i)
#pragma unroll
        for (int j = 0; j < 4; ++j)
            acc[i][j] = (f32x4){0.f, 0.f, 0.f, 0.f};

    auto issue = [&](int itk, int pb) {
        const int kk0 = itk * 32;
#pragma unroll
        for (int s = 0; s < 2; ++s) {
            gl2lds16(hrow[s] + kk0, &As[pb][(wave * 32 + s * 16) * 32]);
            gl2lds16(w2row[s] + kk0, &Bs[pb][(wave * 32 + s * 16) * 32]);
        }
    };

    issue(0, 0);
    issue(1, 1);

    int cur = 0, nxt = 2;
    for (int itk = 0; itk < H1n / 32; ++itk) {
        WAITV(4);
        pipe_barrier();
        {
            int pre = itk + 2;
            if (pre > H1n / 32 - 1) pre = H1n / 32 - 1;
            issue(pre, nxt);
        }
        s16x8 af[4], bf[4];
#pragma unroll
        for (int i = 0; i < 4; ++i) {
            const int r = wm * 64 + i * 16 + ln15;
            af[i] = *(const s16x8*)&As[cur][r * 32 + (q4 ^ (r & 3)) * 8];
        }
#pragma unroll
        for (int jj = 0; jj < 4; ++jj) {
            const int r = wn * 64 + jj * 16 + ln15;
            bf[jj] = *(const s16x8*)&Bs[cur][r * 32 + (q4 ^ (r & 3)) * 8];
        }
#pragma unroll
        for (int i = 0; i < 4; ++i)
#pragma unroll
            for (int jj = 0; jj < 4; ++jj)
                acc[i][jj] = __builtin_amdgcn_mfma_f32_16x16x32_bf16(af[i], bf[jj], acc[i][jj], 0, 0, 0);
        cur = (cur == 2) ? 0 : cur + 1;
        nxt = (nxt == 2) ? 0 : nxt + 1;
    }
    drain_all();

#pragma unroll
    for (int i = 0; i < 4; ++i) {
#pragma unroll
        for (int jj = 0; jj < 4; ++jj) {
            const int e = wn * 64 + jj * 16 + ln15;
            const float bias = b2[e];
#pragma unroll
            for (int rg = 0; rg < 4; ++rg) {
                const int m = wm * 64 + i * 16 + q4 * 4 + rg;
                out[(size_t)(row0 + m) * En + e] = acc[i][jj][rg] + bias;
            }
        }
    }
}

// ---------------- launch ----------------
extern "C" void kernel_launch(void* const* d_in, const int* in_sizes, int n_in,
                              void* d_out, int out_size, void* d_ws, size_t ws_size,
                              hipStream_t stream) {
    const int*   current  = (const int*)d_in[0];
    const float* distance = (const float*)d_in[1];
    const float* masked   = (const float*)d_in[2];
    const float* encoded  = (const float*)d_in[3];
    const float* w1       = (const float*)d_in[4];
    const float* b1       = (const float*)d_in[5];
    const float* w2       = (const float*)d_in[6];
    const float* b2       = (const float*)d_in[7];
    float* out = (float*)d_out;

    char* ws = (char*)d_ws;
    const size_t OFF_IDX  = 0;                          // 64000*10*4   = 2,560,000
    const size_t OFF_ENCB = 2560000;                    // 8,192,000*2  = 16,384,000
    const size_t OFF_MEAN = OFF_ENCB + 16384000;        // 64000*128*2  = 16,384,000
    const size_t OFF_W1B  = OFF_MEAN + 16384000;        // 819200*2     = 1,638,400
    const size_t OFF_W2B  = OFF_W1B + 1638400;          // 81920*2      = 163,840
    const size_t OFF_H    = OFF_W2B + 163840;           // 64000*640*2  = 81,920,000
    int*            idxb   = (int*)(ws + OFF_IDX);
    unsigned short* encb   = (unsigned short*)(ws + OFF_ENCB);
    unsigned short* meanbb = (unsigned short*)(ws + OFF_MEAN);
    unsigned short* w1b    = (unsigned short*)(ws + OFF_W1B);
    unsigned short* w2b    = (unsigned short*)(ws + OFF_W2B);
    unsigned short* hbuf   = (unsigned short*)(ws + OFF_H);

    convw_kernel<<<(Bn * Nn * En / 4 + 255) / 256, 256, 0, stream>>>(encoded, w1, w2, encb, w1b, w2b);
    select_kernel<<<Mn / 4, 256, 0, stream>>>(current, distance, masked, encb, idxb, meanbb);
    gemm1_kernel<<<2504, 256, 0, stream>>>(encb, meanbb, idxb, w1b, b1, hbuf);
    gemm2_kernel<<<Mn / 128, 256, 0, stream>>>(hbuf, w2b, b2, out);
}

// Round 2
// 469.351 us; speedup vs baseline: 1.1226x; 1.1226x over previous
//
#include <hip/hip_runtime.h>
#include <cstdint>
#include <cstddef>

#define Bn   128
#define Rn   500
#define Nn   500
#define Kn   10
#define En   128
#define H1n  640
#define KEn  1280
#define Mn   (Bn * Rn)   // 64000 rows

typedef short s16x8 __attribute__((ext_vector_type(8)));
typedef float f32x4 __attribute__((ext_vector_type(4)));

// fp32 -> bf16 round-to-nearest-even (finite inputs)
__device__ __forceinline__ unsigned short f2bf(float x) {
    union { float f; unsigned int u; } v; v.f = x;
    unsigned int r = v.u + 0x7fffu + ((v.u >> 16) & 1u);
    return (unsigned short)(r >> 16);
}
__device__ __forceinline__ float bf2f(unsigned short u) {
    union { unsigned int u; float f; } v; v.u = ((unsigned int)u) << 16;
    return v.f;
}
// async 16B global->LDS (wave-uniform LDS base + lane*16)
__device__ __forceinline__ void gl2lds16(const void* g, void* l) {
    __builtin_amdgcn_global_load_lds(
        (const __attribute__((address_space(1))) unsigned int*)g,
        (__attribute__((address_space(3))) unsigned int*)l, 16, 0, 0);
}
// full drain (2-phase kernels / prologue cleanup)
__device__ __forceinline__ void drain_all() {
    asm volatile("s_waitcnt vmcnt(0) lgkmcnt(0)" ::: "memory");
}
// counted vmcnt: retire oldest (outstanding-N) VMEM ops, keep N in flight
// ACROSS barriers (T4). vmcnt retires in issue order (m135).
#define WAITV(n) asm volatile("s_waitcnt vmcnt(" #n ")" ::: "memory")
// bare barrier: NO implicit vmcnt(0) drain (unlike __syncthreads); compiler
// memory fence so LDS accesses can't be moved across.
__device__ __forceinline__ void pipe_barrier() {
    __builtin_amdgcn_s_barrier();
    asm volatile("" ::: "memory");
}

// ---------------- kernel 1: fp32 -> bf16 conversions (encoded, w1, w2) ----------------
__global__ void convw_kernel(const float* __restrict__ enc, const float* __restrict__ w1,
                             const float* __restrict__ w2,
                             unsigned short* __restrict__ encb, unsigned short* __restrict__ w1b,
                             unsigned short* __restrict__ w2b) {
    int i = blockIdx.x * 256 + threadIdx.x;   // float4 group index
    if (i < (Bn * Nn * En) / 4) {
        float4 v = ((const float4*)enc)[i];
        ushort4 o; o.x = f2bf(v.x); o.y = f2bf(v.y); o.z = f2bf(v.z); o.w = f2bf(v.w);
        ((ushort4*)encb)[i] = o;
    }
    if (i < (H1n * KEn) / 4) {
        float4 v = ((const float4*)w1)[i];
        ushort4 o; o.x = f2bf(v.x); o.y = f2bf(v.y); o.z = f2bf(v.z); o.w = f2bf(v.w);
        ((ushort4*)w1b)[i] = o;
    }
    if (i < (En * H1n) / 4) {
        float4 v = ((const float4*)w2)[i];
        ushort4 o; o.x = f2bf(v.x); o.y = f2bf(v.y); o.z = f2bf(v.z); o.w = f2bf(v.w);
        ((ushort4*)w2b)[i] = o;
    }
}

// ---------------- kernel 2: fused top-K + pad-avg mean ----------------
__global__ __launch_bounds__(256) void select_kernel(const int* __restrict__ current,
                            const float* __restrict__ distance,
                            const float* __restrict__ masked,
                            const unsigned short* __restrict__ encb,
                            int* __restrict__ idx_out,
                            unsigned short* __restrict__ meanbb) {
    const int row  = blockIdx.x * 4 + (threadIdx.x >> 6);
    const int lane = threadIdx.x & 63;
    const int b    = row / Rn;
    const int cur  = current[row];
    const unsigned int* drow = (const unsigned int*)(distance + ((size_t)b * Nn + cur) * Nn);
    const unsigned int* mrow = (const unsigned int*)(masked + (size_t)row * Nn);

    unsigned long long key[8];
#pragma unroll
    for (int i = 0; i < 8; ++i) {
        int nn = lane + 64 * i;
        unsigned int fb = 0x7F800000u;            // +inf
        if (nn < Nn) {
            unsigned int m = mrow[nn];
            unsigned int d = drow[nn];
            fb = (m == 0xFF800000u) ? 0x7F800000u : d;   // visited -> +inf
        }
        key[i] = ((unsigned long long)fb << 32) | (unsigned int)nn;
    }

    int ids[Kn];
    int myid = Nn;
#pragma unroll
    for (int it = 0; it < Kn; ++it) {
        unsigned long long bk = key[0];
#pragma unroll
        for (int i = 1; i < 8; ++i) bk = (key[i] < bk) ? key[i] : bk;
#pragma unroll
        for (int off = 1; off < 64; off <<= 1) {
            unsigned long long ok = __shfl_xor(bk, off);
            bk = (ok < bk) ? ok : bk;
        }
        const int wid = ((bk >> 32) == 0x7F800000u) ? Nn : (int)(bk & 0xffffffffu);
        ids[it] = wid;
        if (lane == it) myid = wid;
#pragma unroll
        for (int i = 0; i < 8; ++i)
            if (key[i] == bk) key[i] = 0x7F800000FFFFFFFFull;
    }
    if (lane < Kn) idx_out[row * Kn + lane] = myid;

    const unsigned int* encu = (const unsigned int*)(encb + (size_t)b * Nn * En);
    float s0 = 0.f, s1 = 0.f; int cnt = 0;
#pragma unroll
    for (int k = 0; k < Kn; ++k) {
        const int id = ids[k];
        if (id < Nn) {
            unsigned int u = encu[id * (En / 2) + lane];
            s0 += bf2f((unsigned short)(u & 0xffffu));
            s1 += bf2f((unsigned short)(u >> 16));
            cnt++;
        }
    }
    float m0 = 0.f, m1 = 0.f;
    if (cnt > 0) { m0 = s0 / (float)cnt; m1 = s1 / (float)cnt; }
    unsigned int packed = (unsigned int)f2bf(m0) | ((unsigned int)f2bf(m1) << 16);
    ((unsigned int*)meanbb)[(size_t)row * (En / 2) + lane] = packed;
}

// ---------------- kernel 3: GEMM1, 8-phase 256x128 schedule (T3+T4+T5) ----------------
// BM=256, BN=128, BK=64, 512 thr / 8 waves (4M x 2N), per-wave 64x64 out.
// Triple-buffered LDS (A 3x32KB + B 3x16KB = 144KB, 1 block/CU): depth-2
// prefetch so the per-tile wait is vmcnt(6) -- 6 loads (next tile) stay in
// flight across every barrier; vmcnt(0) never appears in the main loop.
// Per K-tile: 4 phases x { ds_reads | 3-load stage bundle -> barrier ->
// setprio(1) + 8 MFMA + setprio(0) -> barrier }.  Neighbor ids live in
// registers (idr[4][10], static-indexed via full unroll) so no stray VMEM
// pollutes the vmcnt arithmetic after the prologue drain.
__global__ __launch_bounds__(512, 2) void gemm1_kernel(
        const unsigned short* __restrict__ encb, const unsigned short* __restrict__ meanbb,
        const int* __restrict__ idxb, const unsigned short* __restrict__ w1b,
        const float* __restrict__ b1, unsigned short* __restrict__ hbuf) {
    extern __shared__ unsigned short lds[];
    unsigned short* const As = lds;                    // 3 * 256*64 shorts
    unsigned short* const Bs = lds + 3 * 256 * 64;     // 3 * 128*64 shorts

    // bijective XCD chunk map (nwg=1250, 8 XCDs: q=156, r=2 -> m204 variant)
    const int p  = blockIdx.x;
    const int x  = p & 7;
    const int rk = p >> 3;
    const int w  = (x < 2 ? x * 157 : 314 + (x - 2) * 156) + rk;
    const int row0 = (w / 5) * 256;
    const int h0   = (w % 5) * 128;

    const int t    = threadIdx.x;
    const int lane = t & 63;
    const int wave = t >> 6;    // 0..7
    const int ln15 = lane & 15;
    const int q4   = lane >> 4;
    const int wm4  = wave & 3;  // M position (4)
    const int wn   = wave >> 2; // N position (2)

    // staging geometry: row = 64 shorts = 128 B = 8 x 16B slots.
    // lane -> row rl8 = lane>>3, slot sc8 = lane&7; slot sc8 holds source
    // chunk sc8^rl8 (linear LDS dest + inverse-swizzled source, m201 pattern).
    const int rl8 = lane >> 3;
    const int sc8 = lane & 7;
    const int cof = (sc8 ^ rl8) * 8;   // source chunk offset (shorts)

    // per-thread staged A rows: ra(s) = s*64 + wave*8 + rl8, s=0..3
    const unsigned short* encBp[4];
    const unsigned short* meanRp[4];
    int grA[4];
#pragma unroll
    for (int s = 0; s < 4; ++s) {
        const int gr = row0 + s * 64 + wave * 8 + rl8;
        grA[s]    = gr;
        encBp[s]  = encb + (size_t)(gr / Rn) * Nn * En;
        meanRp[s] = meanbb + (size_t)gr * En + cof;
    }
    // per-thread staged B rows: rb(s) = s*64 + wave*8 + rl8, s=0..1
    const unsigned short* w1Rp[2];
#pragma unroll
    for (int s = 0; s < 2; ++s)
        w1Rp[s] = w1b + (size_t)(h0 + s * 64 + wave * 8 + rl8) * KEn + cof;

    // preload ALL neighbor ids into registers (static-indexed after unroll)
    int idr[4][Kn];
#pragma unroll
    for (int s = 0; s < 4; ++s)
#pragma unroll
        for (int j = 0; j < Kn; ++j)
            idr[s][j] = idxb[grA[s] * Kn + j];
    WAITV(0);   // ids landed -> only stage DMAs are counted from here on

    f32x4 acc[4][4];
#pragma unroll
    for (int i = 0; i < 4; ++i)
#pragma unroll
        for (int j = 0; j < 4; ++j)
            acc[i][j] = (f32x4){0.f, 0.f, 0.f, 0.f};

    // stage bundles: 3 loads each. bundle0 = A rows 0..127 + B rows 0..63,
    // bundle1 = A rows 128..255 + B rows 64..127 (each K-tile = 2 bundles).
    auto stA = [&](int s, int j, int e0, int b) {
        const int id = idr[s][j];
        const unsigned short* src = (id < Nn)
            ? (encBp[s] + (size_t)id * En + e0 + cof)
            : (meanRp[s] + e0);
        gl2lds16(src, As + (size_t)b * (256 * 64) + (s * 64 + wave * 8) * 64);
    };
    auto stB = [&](int s, int kt, int b) {
        gl2lds16(w1Rp[s] + kt * 64, Bs + (size_t)b * (128 * 64) + (s * 64 + wave * 8) * 64);
    };
    auto bundle0 = [&](int kt, int b) {
        const int j = kt >> 1, e0 = (kt & 1) * 64;
        stA(0, j, e0, b); stA(1, j, e0, b); stB(0, kt, b);
    };
    auto bundle1 = [&](int kt, int b) {
        const int j = kt >> 1, e0 = (kt & 1) * 64;
        stA(2, j, e0, b); stA(3, j, e0, b); stB(1, kt, b);
    };

    // prologue: stage tiles 0 and 1 (12 loads), retire tile 0's 6, publish.
    bundle0(0, 0); bundle1(0, 0);
    bundle0(1, 1); bundle1(1, 1);
    WAITV(6);
    pipe_barrier();

    const int rA = wm4 * 64 + ln15;   // + i*16  -> A row
    const int rB = wn  * 64 + ln15;   // + jj*16 -> B row
    const int s7 = ln15 & 7;          // row&7 for the read-side XOR swizzle
    const int sl0 = (q4 ^ s7) * 8;        // kk=0  slot offset (shorts)
    const int sl1 = ((4 + q4) ^ s7) * 8;  // kk=32 slot offset

#define MFMA16(a, bvec, c) c = __builtin_amdgcn_mfma_f32_16x16x32_bf16(a, bvec, c, 0, 0, 0)

#pragma unroll
    for (int kt = 0; kt < 20; ++kt) {
        const int cb = kt % 3;
        const unsigned short* Ab = As + cb * (256 * 64);
        const unsigned short* Bb = Bs + cb * (128 * 64);
        s16x8 af0, af1, af2, af3, bq0, bq1;

        // ---- phase 0: kk=0, jj=0..1  (+ stage bundle0 of kt+2)
        af0 = *(const s16x8*)(Ab + (rA +  0) * 64 + sl0);
        af1 = *(const s16x8*)(Ab + (rA + 16) * 64 + sl0);
        af2 = *(const s16x8*)(Ab + (rA + 32) * 64 + sl0);
        af3 = *(const s16x8*)(Ab + (rA + 48) * 64 + sl0);
        bq0 = *(const s16x8*)(Bb + (rB +  0) * 64 + sl0);
        bq1 = *(const s16x8*)(Bb + (rB + 16) * 64 + sl0);
        if (kt + 2 < 20) bundle0(kt + 2, (kt + 2) % 3);
        pipe_barrier();
        __builtin_amdgcn_s_setprio(1);
        MFMA16(af0, bq0, acc[0][0]); MFMA16(af1, bq0, acc[1][0]);
        MFMA16(af2, bq0, acc[2][0]); MFMA16(af3, bq0, acc[3][0]);
        MFMA16(af0, bq1, acc[0][1]); MFMA16(af1, bq1, acc[1][1]);
        MFMA16(af2, bq1, acc[2][1]); MFMA16(af3, bq1, acc[3][1]);
        __builtin_amdgcn_s_setprio(0);
        pipe_barrier();

        // ---- phase 1: kk=0, jj=2..3
        bq0 = *(const s16x8*)(Bb + (rB + 32) * 64 + sl0);
        bq1 = *(const s16x8*)(Bb + (rB + 48) * 64 + sl0);
        pipe_barrier();
        __builtin_amdgcn_s_setprio(1);
        MFMA16(af0, bq0, acc[0][2]); MFMA16(af1, bq0, acc[1][2]);
        MFMA16(af2, bq0, acc[2][2]); MFMA16(af3, bq0, acc[3][2]);
        MFMA16(af0, bq1, acc[0][3]); MFMA16(af1, bq1, acc[1][3]);
        MFMA16(af2, bq1, acc[2][3]); MFMA16(af3, bq1, acc[3][3]);
        __builtin_amdgcn_s_setprio(0);
        pipe_barrier();

        // ---- phase 2: kk=32, jj=0..1  (+ stage bundle1 of kt+2)
        af0 = *(const s16x8*)(Ab + (rA +  0) * 64 + sl1);
        af1 = *(const s16x8*)(Ab + (rA + 16) * 64 + sl1);
        af2 = *(const s16x8*)(Ab + (rA + 32) * 64 + sl1);
        af3 = *(const s16x8*)(Ab + (rA + 48) * 64 + sl1);
        bq0 = *(const s16x8*)(Bb + (rB +  0) * 64 + sl1);
        bq1 = *(const s16x8*)(Bb + (rB + 16) * 64 + sl1);
        if (kt + 2 < 20) bundle1(kt + 2, (kt + 2) % 3);
        pipe_barrier();
        __builtin_amdgcn_s_setprio(1);
        MFMA16(af0, bq0, acc[0][0]); MFMA16(af1, bq0, acc[1][0]);
        MFMA16(af2, bq0, acc[2][0]); MFMA16(af3, bq0, acc[3][0]);
        MFMA16(af0, bq1, acc[0][1]); MFMA16(af1, bq1, acc[1][1]);
        MFMA16(af2, bq1, acc[2][1]); MFMA16(af3, bq1, acc[3][1]);
        __builtin_amdgcn_s_setprio(0);
        pipe_barrier();

        // ---- phase 3: kk=32, jj=2..3, then counted tile-end wait
        bq0 = *(const s16x8*)(Bb + (rB + 32) * 64 + sl1);
        bq1 = *(const s16x8*)(Bb + (rB + 48) * 64 + sl1);
        pipe_barrier();
        __builtin_amdgcn_s_setprio(1);
        MFMA16(af0, bq0, acc[0][2]); MFMA16(af1, bq0, acc[1][2]);
        MFMA16(af2, bq0, acc[2][2]); MFMA16(af3, bq0, acc[3][2]);
        MFMA16(af0, bq1, acc[0][3]); MFMA16(af1, bq1, acc[1][3]);
        MFMA16(af2, bq1, acc[2][3]); MFMA16(af3, bq1, acc[3][3]);
        __builtin_amdgcn_s_setprio(0);
        // retire kt+1's 6 loads (oldest); keep kt+2's 6 in flight.
        if (kt + 2 < 20)      { WAITV(6); }
        else if (kt + 1 < 20) { WAITV(0); }   // tail: no kt+2 issued
        pipe_barrier();
    }
#undef MFMA16

    // ---- epilogue: bias + relu + bf16 store ----
#pragma unroll
    for (int i = 0; i < 4; ++i) {
#pragma unroll
        for (int jj = 0; jj < 4; ++jj) {
            const int h = h0 + wn * 64 + jj * 16 + ln15;
            const float bias = b1[h];
#pragma unroll
            for (int rg = 0; rg < 4; ++rg) {
                const int m = wm4 * 64 + i * 16 + q4 * 4 + rg;
                float vv = acc[i][jj][rg] + bias;
                vv = fmaxf(vv, 0.f);
                hbuf[(size_t)(row0 + m) * H1n + h] = f2bf(vv);
            }
        }
    }
}

// ---------------- kernel 4: GEMM2, BK=32 double-buffer (R0-verbatim) ----------------
__global__ __launch_bounds__(256, 4) void gemm2_kernel(
        const unsigned short* __restrict__ hbuf, const unsigned short* __restrict__ w2b,
        const float* __restrict__ b2, float* __restrict__ out) {
    __shared__ alignas(16) unsigned short As[2][128 * 32];
    __shared__ alignas(16) unsigned short Bs[2][128 * 32];

    const int row0 = blockIdx.x * 128;
    const int t    = threadIdx.x;
    const int lane = t & 63;
    const int wave = t >> 6;
    const int ln15 = lane & 15;
    const int q4   = lane >> 4;
    const int wm   = wave & 1;
    const int wn   = wave >> 1;

    const int rl   = lane >> 2;
    const int sc   = lane & 3;
    const int coff = (sc ^ (rl & 3)) * 8;

    const unsigned short* hrow[2];
    const unsigned short* w2row[2];
#pragma unroll
    for (int s = 0; s < 2; ++s) {
        const int lr = wave * 32 + s * 16 + rl;
        hrow[s]  = hbuf + (size_t)(row0 + lr) * H1n + coff;
        w2row[s] = w2b + (size_t)lr * H1n + coff;
    }

    f32x4 acc[4][4];
#pragma unroll
    for (int i = 0; i < 4; ++i)
#pragma unroll
        for (int j = 0; j < 4; ++j)
            acc[i][j] = (f32x4){0.f, 0.f, 0.f, 0.f};

    auto issue = [&](int itk, int pb) {
        const int kk0 = itk * 32;
#pragma unroll
        for (int s = 0; s < 2; ++s) {
            gl2lds16(hrow[s] + kk0, &As[pb][(wave * 32 + s * 16) * 32]);
            gl2lds16(w2row[s] + kk0, &Bs[pb][(wave * 32 + s * 16) * 32]);
        }
    };

    issue(0, 0);

    for (int itk = 0; itk < H1n / 32; ++itk) {
        const int cur = itk & 1;
        drain_all();
        __syncthreads();
        if (itk + 1 < H1n / 32) issue(itk + 1, cur ^ 1);
        s16x8 af[4], bf[4];
#pragma unroll
        for (int i = 0; i < 4; ++i) {
            const int r = wm * 64 + i * 16 + ln15;
            af[i] = *(const s16x8*)&As[cur][r * 32 + (q4 ^ (r & 3)) * 8];
        }
#pragma unroll
        for (int jj = 0; jj < 4; ++jj) {
            const int r = wn * 64 + jj * 16 + ln15;
            bf[jj] = *(const s16x8*)&Bs[cur][r * 32 + (q4 ^ (r & 3)) * 8];
        }
#pragma unroll
        for (int i = 0; i < 4; ++i)
#pragma unroll
            for (int jj = 0; jj < 4; ++jj)
                acc[i][jj] = __builtin_amdgcn_mfma_f32_16x16x32_bf16(af[i], bf[jj], acc[i][jj], 0, 0, 0);
    }

#pragma unroll
    for (int i = 0; i < 4; ++i) {
#pragma unroll
        for (int jj = 0; jj < 4; ++jj) {
            const int e = wn * 64 + jj * 16 + ln15;
            const float bias = b2[e];
#pragma unroll
            for (int rg = 0; rg < 4; ++rg) {
                const int m = wm * 64 + i * 16 + q4 * 4 + rg;
                out[(size_t)(row0 + m) * En + e] = acc[i][jj][rg] + bias;
            }
        }
    }
}

// ---------------- launch ----------------
extern "C" void kernel_launch(void* const* d_in, const int* in_sizes, int n_in,
                              void* d_out, int out_size, void* d_ws, size_t ws_size,
                              hipStream_t stream) {
    const int*   current  = (const int*)d_in[0];
    const float* distance = (const float*)d_in[1];
    const float* masked   = (const float*)d_in[2];
    const float* encoded  = (const float*)d_in[3];
    const float* w1       = (const float*)d_in[4];
    const float* b1       = (const float*)d_in[5];
    const float* w2       = (const float*)d_in[6];
    const float* b2       = (const float*)d_in[7];
    float* out = (float*)d_out;

    char* ws = (char*)d_ws;
    const size_t OFF_IDX  = 0;                          // 64000*10*4   = 2,560,000
    const size_t OFF_ENCB = 2560000;                    // 8,192,000*2  = 16,384,000
    const size_t OFF_MEAN = OFF_ENCB + 16384000;        // 64000*128*2  = 16,384,000
    const size_t OFF_W1B  = OFF_MEAN + 16384000;        // 819200*2     = 1,638,400
    const size_t OFF_W2B  = OFF_W1B + 1638400;          // 81920*2      = 163,840
    const size_t OFF_H    = OFF_W2B + 163840;           // 64000*640*2  = 81,920,000
    int*            idxb   = (int*)(ws + OFF_IDX);
    unsigned short* encb   = (unsigned short*)(ws + OFF_ENCB);
    unsigned short* meanbb = (unsigned short*)(ws + OFF_MEAN);
    unsigned short* w1b    = (unsigned short*)(ws + OFF_W1B);
    unsigned short* w2b    = (unsigned short*)(ws + OFF_W2B);
    unsigned short* hbuf   = (unsigned short*)(ws + OFF_H);

    // 144 KB dynamic LDS for gemm1 (3-buffer A + 3-buffer B)
    static bool s_attr = false;
    if (!s_attr) {
        hipFuncSetAttribute(reinterpret_cast<const void*>(gemm1_kernel),
                            hipFuncAttributeMaxDynamicSharedMemorySize, 147456);
        s_attr = true;
    }

    convw_kernel<<<(Bn * Nn * En / 4 + 255) / 256, 256, 0, stream>>>(encoded, w1, w2, encb, w1b, w2b);
    select_kernel<<<Mn / 4, 256, 0, stream>>>(current, distance, masked, encb, idxb, meanbb);
    gemm1_kernel<<<1250, 512, 147456, stream>>>(encb, meanbb, idxb, w1b, b1, hbuf);
    gemm2_kernel<<<Mn / 128, 256, 0, stream>>>(hbuf, w2b, b2, out);
}

// Round 3
// 467.463 us; speedup vs baseline: 1.1272x; 1.0040x over previous
//
#include <hip/hip_runtime.h>
#include <cstdint>
#include <cstddef>

#define Bn   128
#define Rn   500
#define Nn   500
#define Kn   10
#define En   128
#define H1n  640
#define KEn  1280
#define Mn   (Bn * Rn)   // 64000 rows

typedef short s16x8 __attribute__((ext_vector_type(8)));
typedef float f32x4 __attribute__((ext_vector_type(4)));

// fp32 -> bf16 round-to-nearest-even (finite inputs)
__device__ __forceinline__ unsigned short f2bf(float x) {
    union { float f; unsigned int u; } v; v.f = x;
    unsigned int r = v.u + 0x7fffu + ((v.u >> 16) & 1u);
    return (unsigned short)(r >> 16);
}
__device__ __forceinline__ float bf2f(unsigned short u) {
    union { unsigned int u; float f; } v; v.u = ((unsigned int)u) << 16;
    return v.f;
}
// async 16B global->LDS (wave-uniform LDS base + lane*16)
__device__ __forceinline__ void gl2lds16(const void* g, void* l) {
    __builtin_amdgcn_global_load_lds(
        (const __attribute__((address_space(1))) unsigned int*)g,
        (__attribute__((address_space(3))) unsigned int*)l, 16, 0, 0);
}
// full drain (prologue cleanup only — never in main loops)
__device__ __forceinline__ void drain_all() {
    asm volatile("s_waitcnt vmcnt(0) lgkmcnt(0)" ::: "memory");
}
// counted vmcnt: retire oldest (outstanding-N) VMEM ops, keep N in flight
// ACROSS barriers (T4). vmcnt retires in issue order (m135).
#define WAITV(n) asm volatile("s_waitcnt vmcnt(" #n ")" ::: "memory")
// bare barrier: NO implicit vmcnt(0) drain (unlike __syncthreads)
__device__ __forceinline__ void pipe_barrier() {
    __builtin_amdgcn_s_barrier();
    asm volatile("" ::: "memory");
}

// ---------------- kernel 1: fp32 -> bf16 conversions (encoded, w1, w2) ----------------
__global__ void convw_kernel(const float* __restrict__ enc, const float* __restrict__ w1,
                             const float* __restrict__ w2,
                             unsigned short* __restrict__ encb, unsigned short* __restrict__ w1b,
                             unsigned short* __restrict__ w2b) {
    int i = blockIdx.x * 256 + threadIdx.x;   // float4 group index
    if (i < (Bn * Nn * En) / 4) {
        float4 v = ((const float4*)enc)[i];
        ushort4 o; o.x = f2bf(v.x); o.y = f2bf(v.y); o.z = f2bf(v.z); o.w = f2bf(v.w);
        ((ushort4*)encb)[i] = o;
    }
    if (i < (H1n * KEn) / 4) {
        float4 v = ((const float4*)w1)[i];
        ushort4 o; o.x = f2bf(v.x); o.y = f2bf(v.y); o.z = f2bf(v.z); o.w = f2bf(v.w);
        ((ushort4*)w1b)[i] = o;
    }
    if (i < (En * H1n) / 4) {
        float4 v = ((const float4*)w2)[i];
        ushort4 o; o.x = f2bf(v.x); o.y = f2bf(v.y); o.z = f2bf(v.z); o.w = f2bf(v.w);
        ((ushort4*)w2b)[i] = o;
    }
}

// ---------------- kernel 2: fused top-K + pad-avg mean ----------------
__global__ __launch_bounds__(256) void select_kernel(const int* __restrict__ current,
                            const float* __restrict__ distance,
                            const float* __restrict__ masked,
                            const unsigned short* __restrict__ encb,
                            int* __restrict__ idx_out,
                            unsigned short* __restrict__ meanbb) {
    const int row  = blockIdx.x * 4 + (threadIdx.x >> 6);
    const int lane = threadIdx.x & 63;
    const int b    = row / Rn;
    const int cur  = current[row];
    const unsigned int* drow = (const unsigned int*)(distance + ((size_t)b * Nn + cur) * Nn);
    const unsigned int* mrow = (const unsigned int*)(masked + (size_t)row * Nn);

    unsigned long long key[8];
#pragma unroll
    for (int i = 0; i < 8; ++i) {
        int nn = lane + 64 * i;
        unsigned int fb = 0x7F800000u;            // +inf
        if (nn < Nn) {
            unsigned int m = mrow[nn];
            unsigned int d = drow[nn];
            fb = (m == 0xFF800000u) ? 0x7F800000u : d;   // visited -> +inf
        }
        key[i] = ((unsigned long long)fb << 32) | (unsigned int)nn;
    }

    int ids[Kn];
    int myid = Nn;
#pragma unroll
    for (int it = 0; it < Kn; ++it) {
        unsigned long long bk = key[0];
#pragma unroll
        for (int i = 1; i < 8; ++i) bk = (key[i] < bk) ? key[i] : bk;
#pragma unroll
        for (int off = 1; off < 64; off <<= 1) {
            unsigned long long ok = __shfl_xor(bk, off);
            bk = (ok < bk) ? ok : bk;
        }
        const int wid = ((bk >> 32) == 0x7F800000u) ? Nn : (int)(bk & 0xffffffffu);
        ids[it] = wid;
        if (lane == it) myid = wid;
#pragma unroll
        for (int i = 0; i < 8; ++i)
            if (key[i] == bk) key[i] = 0x7F800000FFFFFFFFull;
    }
    if (lane < Kn) idx_out[row * Kn + lane] = myid;

    const unsigned int* encu = (const unsigned int*)(encb + (size_t)b * Nn * En);
    float s0 = 0.f, s1 = 0.f; int cnt = 0;
#pragma unroll
    for (int k = 0; k < Kn; ++k) {
        const int id = ids[k];
        if (id < Nn) {
            unsigned int u = encu[id * (En / 2) + lane];
            s0 += bf2f((unsigned short)(u & 0xffffu));
            s1 += bf2f((unsigned short)(u >> 16));
            cnt++;
        }
    }
    float m0 = 0.f, m1 = 0.f;
    if (cnt > 0) { m0 = s0 / (float)cnt; m1 = s1 / (float)cnt; }
    unsigned int packed = (unsigned int)f2bf(m0) | ((unsigned int)f2bf(m1) << 16);
    ((unsigned int*)meanbb)[(size_t)row * (En / 2) + lane] = packed;
}

// ---------------- kernel 3: GEMM1, 8-wave 256x128, BK=32, triple-buffer, 2 blocks/CU ----
// Same wave geometry as R2 (8 waves 4Mx2N, per-wave 64x64) but BK halved so the
// triple-buffered LDS is 77 KB -> TWO blocks/CU (16 waves, 4/SIMD): cross-block
// desync hides barriers/stage latency the single-block R2 config exposed.
// Depth-2 prefetch, counted WAITV(3) at tile end (never 0 in main loop).
__global__ __launch_bounds__(512, 4) void gemm1_kernel(
        const unsigned short* __restrict__ encb, const unsigned short* __restrict__ meanbb,
        const int* __restrict__ idxb, const unsigned short* __restrict__ w1b,
        const float* __restrict__ b1, unsigned short* __restrict__ hbuf) {
    extern __shared__ unsigned short lds[];
    unsigned short* const As   = lds;                              // 3 * 256*32
    unsigned short* const Bs   = lds + 3 * 256 * 32;               // 3 * 128*32
    unsigned short* const idxs = lds + 3 * 256 * 32 + 3 * 128 * 32; // 2560 u16

    // bijective XCD chunk map (nwg=1250, 8 XCDs: q=156, r=2)
    const int p  = blockIdx.x;
    const int x  = p & 7;
    const int rk = p >> 3;
    const int w  = (x < 2 ? x * 157 : 314 + (x - 2) * 156) + rk;
    const int row0 = (w / 5) * 256;
    const int h0   = (w % 5) * 128;

    const int t    = threadIdx.x;
    const int lane = t & 63;
    const int wave = t >> 6;    // 0..7
    const int ln15 = lane & 15;
    const int q4   = lane >> 4;
    const int wm4  = wave & 3;  // M position (4)
    const int wn   = wave >> 2; // N position (2)

    // stage neighbor ids (256 rows x 10) as u16 into LDS (ds-reads are
    // lgkm-counted, so the vmcnt pipeline arithmetic stays exact)
    for (int i = t; i < 256 * Kn; i += 512)
        idxs[i] = (unsigned short)idxb[row0 * Kn + i];

    // staging geometry: row = 32 shorts = 64 B = 4 x 16B slots.
    // lane -> row rl = lane>>2, slot sc = lane&3; slot sc holds chunk sc^(rl&3).
    const int rl   = lane >> 2;
    const int sc   = lane & 3;
    const int coff = (sc ^ (rl & 3)) * 8;   // source chunk offset (shorts)

    int lrowA[2];
    const unsigned short* encB[2];
    const unsigned short* meanR[2];
#pragma unroll
    for (int s = 0; s < 2; ++s) {
        lrowA[s] = wave * 32 + s * 16 + rl;
        const int gr = row0 + lrowA[s];
        encB[s]  = encb + (size_t)(gr / Rn) * Nn * En;
        meanR[s] = meanbb + (size_t)gr * En + coff;
    }
    const int lrowB = wave * 16 + rl;
    const unsigned short* w1R = w1b + (size_t)(h0 + lrowB) * KEn + coff;

    f32x4 acc[4][4];
#pragma unroll
    for (int i = 0; i < 4; ++i)
#pragma unroll
        for (int j = 0; j < 4; ++j)
            acc[i][j] = (f32x4){0.f, 0.f, 0.f, 0.f};

    // per tile: issueA = 2 loads (A rows), issueB = 1 load (B rows): 3/thread
    auto issueA = [&](int kt, int cb) {
        const int j  = kt >> 2;             // neighbor slot
        const int e0 = (kt & 3) * 32;       // quarter of embedding row
#pragma unroll
        for (int s = 0; s < 2; ++s) {
            const int id = idxs[lrowA[s] * Kn + j];
            const unsigned short* src = (id < Nn)
                ? (encB[s] + (size_t)id * En + e0 + coff)
                : (meanR[s] + e0);
            gl2lds16(src, As + (size_t)cb * (256 * 32) + (wave * 32 + s * 16) * 32);
        }
    };
    auto issueB = [&](int kt, int cb) {
        gl2lds16(w1R + kt * 32, Bs + (size_t)cb * (128 * 32) + (wave * 16) * 32);
    };

    drain_all();
    __syncthreads();          // idxs visible; vmcnt clean slate
    issueA(0, 0); issueB(0, 0);
    issueA(1, 1); issueB(1, 1);
    WAITV(3);                 // tile0's 3 landed; tile1's 3 stay in flight
    pipe_barrier();

    const int rA  = wm4 * 64 + ln15;
    const int rB  = wn  * 64 + ln15;
    const int slA = (q4 ^ (rA & 3)) * 8;   // read-side XOR slot (row&3 const: +16 steps)
    const int slB = (q4 ^ (rB & 3)) * 8;

#define MFMA16(a, bvec, c) c = __builtin_amdgcn_mfma_f32_16x16x32_bf16(a, bvec, c, 0, 0, 0)

#pragma unroll
    for (int kt = 0; kt < 40; ++kt) {
        const int cb = kt % 3;
        const unsigned short* Ab = As + cb * (256 * 32);
        const unsigned short* Bb = Bs + cb * (128 * 32);
        s16x8 af0, af1, af2, af3, bq0, bq1;

        // ---- phase 0: jj=0..1  (+ stage A of kt+2)
        af0 = *(const s16x8*)(Ab + (rA +  0) * 32 + slA);
        af1 = *(const s16x8*)(Ab + (rA + 16) * 32 + slA);
        af2 = *(const s16x8*)(Ab + (rA + 32) * 32 + slA);
        af3 = *(const s16x8*)(Ab + (rA + 48) * 32 + slA);
        bq0 = *(const s16x8*)(Bb + (rB +  0) * 32 + slB);
        bq1 = *(const s16x8*)(Bb + (rB + 16) * 32 + slB);
        if (kt + 2 < 40) issueA(kt + 2, (kt + 2) % 3);
        pipe_barrier();
        __builtin_amdgcn_s_setprio(1);
        MFMA16(af0, bq0, acc[0][0]); MFMA16(af1, bq0, acc[1][0]);
        MFMA16(af2, bq0, acc[2][0]); MFMA16(af3, bq0, acc[3][0]);
        MFMA16(af0, bq1, acc[0][1]); MFMA16(af1, bq1, acc[1][1]);
        MFMA16(af2, bq1, acc[2][1]); MFMA16(af3, bq1, acc[3][1]);
        __builtin_amdgcn_s_setprio(0);
        pipe_barrier();

        // ---- phase 1: jj=2..3  (+ stage B of kt+2, counted tile-end wait)
        bq0 = *(const s16x8*)(Bb + (rB + 32) * 32 + slB);
        bq1 = *(const s16x8*)(Bb + (rB + 48) * 32 + slB);
        if (kt + 2 < 40) issueB(kt + 2, (kt + 2) % 3);
        pipe_barrier();
        __builtin_amdgcn_s_setprio(1);
        MFMA16(af0, bq0, acc[0][2]); MFMA16(af1, bq0, acc[1][2]);
        MFMA16(af2, bq0, acc[2][2]); MFMA16(af3, bq0, acc[3][2]);
        MFMA16(af0, bq1, acc[0][3]); MFMA16(af1, bq1, acc[1][3]);
        MFMA16(af2, bq1, acc[2][3]); MFMA16(af3, bq1, acc[3][3]);
        __builtin_amdgcn_s_setprio(0);
        // retire kt+1's 3 loads; keep kt+2's 3 in flight (never 0 mid-loop)
        if (kt + 2 < 40)      { WAITV(3); }
        else if (kt + 1 < 40) { WAITV(0); }   // tail: no kt+2 issued
        pipe_barrier();
    }
#undef MFMA16

    // ---- epilogue: bias + relu + bf16 store ----
#pragma unroll
    for (int i = 0; i < 4; ++i) {
#pragma unroll
        for (int jj = 0; jj < 4; ++jj) {
            const int h = h0 + wn * 64 + jj * 16 + ln15;
            const float bias = b1[h];
#pragma unroll
            for (int rg = 0; rg < 4; ++rg) {
                const int m = wm4 * 64 + i * 16 + q4 * 4 + rg;
                float vv = acc[i][jj][rg] + bias;
                vv = fmaxf(vv, 0.f);
                hbuf[(size_t)(row0 + m) * H1n + h] = f2bf(vv);
            }
        }
    }
}

// ---------------- kernel 4: GEMM2, 4-wave 128x128, BK=32, triple-buffer, 3 blocks/CU ----
// Same counted-vmcnt skeleton as gemm1. Grid 500, 48 KB LDS -> 3 blocks/CU.
__global__ __launch_bounds__(256, 4) void gemm2_kernel(
        const unsigned short* __restrict__ hbuf, const unsigned short* __restrict__ w2b,
        const float* __restrict__ b2, float* __restrict__ out) {
    __shared__ alignas(16) unsigned short As[3][128 * 32];
    __shared__ alignas(16) unsigned short Bs[3][128 * 32];

    const int row0 = blockIdx.x * 128;
    const int t    = threadIdx.x;
    const int lane = t & 63;
    const int wave = t >> 6;    // 0..3
    const int ln15 = lane & 15;
    const int q4   = lane >> 4;
    const int wm   = wave & 1;
    const int wn   = wave >> 1;

    const int rl   = lane >> 2;
    const int sc   = lane & 3;
    const int coff = (sc ^ (rl & 3)) * 8;

    const unsigned short* hrow[2];
    const unsigned short* w2row[2];
#pragma unroll
    for (int s = 0; s < 2; ++s) {
        const int lr = wave * 32 + s * 16 + rl;
        hrow[s]  = hbuf + (size_t)(row0 + lr) * H1n + coff;
        w2row[s] = w2b + (size_t)lr * H1n + coff;
    }

    f32x4 acc[4][4];
#pragma unroll
    for (int i = 0; i < 4; ++i)
#pragma unroll
        for (int j = 0; j < 4; ++j)
            acc[i][j] = (f32x4){0.f, 0.f, 0.f, 0.f};

    auto issueA = [&](int kt, int cb) {
#pragma unroll
        for (int s = 0; s < 2; ++s)
            gl2lds16(hrow[s] + kt * 32, &As[cb][(wave * 32 + s * 16) * 32]);
    };
    auto issueB = [&](int kt, int cb) {
#pragma unroll
        for (int s = 0; s < 2; ++s)
            gl2lds16(w2row[s] + kt * 32, &Bs[cb][(wave * 32 + s * 16) * 32]);
    };

    issueA(0, 0); issueB(0, 0);
    issueA(1, 1); issueB(1, 1);
    WAITV(4);                 // tile0's 4 landed; tile1's 4 in flight
    pipe_barrier();

    const int rA  = wm * 64 + ln15;
    const int rB  = wn * 64 + ln15;
    const int slA = (q4 ^ (rA & 3)) * 8;
    const int slB = (q4 ^ (rB & 3)) * 8;

#define MFMA16(a, bvec, c) c = __builtin_amdgcn_mfma_f32_16x16x32_bf16(a, bvec, c, 0, 0, 0)

#pragma unroll
    for (int kt = 0; kt < 20; ++kt) {
        const int cb = kt % 3;
        const unsigned short* Ab = As[cb];
        const unsigned short* Bb = Bs[cb];
        s16x8 af0, af1, af2, af3, bq0, bq1;

        // ---- phase 0: jj=0..1  (+ stage A of kt+2)
        af0 = *(const s16x8*)(Ab + (rA +  0) * 32 + slA);
        af1 = *(const s16x8*)(Ab + (rA + 16) * 32 + slA);
        af2 = *(const s16x8*)(Ab + (rA + 32) * 32 + slA);
        af3 = *(const s16x8*)(Ab + (rA + 48) * 32 + slA);
        bq0 = *(const s16x8*)(Bb + (rB +  0) * 32 + slB);
        bq1 = *(const s16x8*)(Bb + (rB + 16) * 32 + slB);
        if (kt + 2 < 20) issueA(kt + 2, (kt + 2) % 3);
        pipe_barrier();
        __builtin_amdgcn_s_setprio(1);
        MFMA16(af0, bq0, acc[0][0]); MFMA16(af1, bq0, acc[1][0]);
        MFMA16(af2, bq0, acc[2][0]); MFMA16(af3, bq0, acc[3][0]);
        MFMA16(af0, bq1, acc[0][1]); MFMA16(af1, bq1, acc[1][1]);
        MFMA16(af2, bq1, acc[2][1]); MFMA16(af3, bq1, acc[3][1]);
        __builtin_amdgcn_s_setprio(0);
        pipe_barrier();

        // ---- phase 1: jj=2..3  (+ stage B of kt+2, counted tile-end wait)
        bq0 = *(const s16x8*)(Bb + (rB + 32) * 32 + slB);
        bq1 = *(const s16x8*)(Bb + (rB + 48) * 32 + slB);
        if (kt + 2 < 20) issueB(kt + 2, (kt + 2) % 3);
        pipe_barrier();
        __builtin_amdgcn_s_setprio(1);
        MFMA16(af0, bq0, acc[0][2]); MFMA16(af1, bq0, acc[1][2]);
        MFMA16(af2, bq0, acc[2][2]); MFMA16(af3, bq0, acc[3][2]);
        MFMA16(af0, bq1, acc[0][3]); MFMA16(af1, bq1, acc[1][3]);
        MFMA16(af2, bq1, acc[2][3]); MFMA16(af3, bq1, acc[3][3]);
        __builtin_amdgcn_s_setprio(0);
        if (kt + 2 < 20)      { WAITV(4); }
        else if (kt + 1 < 20) { WAITV(0); }
        pipe_barrier();
    }
#undef MFMA16

#pragma unroll
    for (int i = 0; i < 4; ++i) {
#pragma unroll
        for (int jj = 0; jj < 4; ++jj) {
            const int e = wn * 64 + jj * 16 + ln15;
            const float bias = b2[e];
#pragma unroll
            for (int rg = 0; rg < 4; ++rg) {
                const int m = wm * 64 + i * 16 + q4 * 4 + rg;
                out[(size_t)(row0 + m) * En + e] = acc[i][jj][rg] + bias;
            }
        }
    }
}

// ---------------- launch ----------------
extern "C" void kernel_launch(void* const* d_in, const int* in_sizes, int n_in,
                              void* d_out, int out_size, void* d_ws, size_t ws_size,
                              hipStream_t stream) {
    const int*   current  = (const int*)d_in[0];
    const float* distance = (const float*)d_in[1];
    const float* masked   = (const float*)d_in[2];
    const float* encoded  = (const float*)d_in[3];
    const float* w1       = (const float*)d_in[4];
    const float* b1       = (const float*)d_in[5];
    const float* w2       = (const float*)d_in[6];
    const float* b2       = (const float*)d_in[7];
    float* out = (float*)d_out;

    char* ws = (char*)d_ws;
    const size_t OFF_IDX  = 0;                          // 64000*10*4   = 2,560,000
    const size_t OFF_ENCB = 2560000;                    // 8,192,000*2  = 16,384,000
    const size_t OFF_MEAN = OFF_ENCB + 16384000;        // 64000*128*2  = 16,384,000
    const size_t OFF_W1B  = OFF_MEAN + 16384000;        // 819200*2     = 1,638,400
    const size_t OFF_W2B  = OFF_W1B + 1638400;          // 81920*2      = 163,840
    const size_t OFF_H    = OFF_W2B + 163840;           // 64000*640*2  = 81,920,000
    int*            idxb   = (int*)(ws + OFF_IDX);
    unsigned short* encb   = (unsigned short*)(ws + OFF_ENCB);
    unsigned short* meanbb = (unsigned short*)(ws + OFF_MEAN);
    unsigned short* w1b    = (unsigned short*)(ws + OFF_W1B);
    unsigned short* w2b    = (unsigned short*)(ws + OFF_W2B);
    unsigned short* hbuf   = (unsigned short*)(ws + OFF_H);

    // gemm1 dynamic LDS: 3*(16KB A + 8KB B) + 5KB idx = 78848 B (2 blocks/CU)
    static bool s_attr = false;
    if (!s_attr) {
        hipFuncSetAttribute(reinterpret_cast<const void*>(gemm1_kernel),
                            hipFuncAttributeMaxDynamicSharedMemorySize, 78848);
        s_attr = true;
    }

    convw_kernel<<<(Bn * Nn * En / 4 + 255) / 256, 256, 0, stream>>>(encoded, w1, w2, encb, w1b, w2b);
    select_kernel<<<Mn / 4, 256, 0, stream>>>(current, distance, masked, encb, idxb, meanbb);
    gemm1_kernel<<<1250, 512, 78848, stream>>>(encb, meanbb, idxb, w1b, b1, hbuf);
    gemm2_kernel<<<Mn / 128, 256, 0, stream>>>(hbuf, w2b, b2, out);
}